// Round 7
// baseline (182.396 us; speedup 1.0000x reference)
//
#include <hip/hip_runtime.h>

#define NV  778
#define NBP 135
#define NK  146    // coef: 1 (template) + 10 (beta) + 135 (pose_feature)
#define NKP 148    // padded to multiple of 4 (rows 146,147 are zeros)
#define GC  8      // batches per kC block

// Finger vertex ids
#define FV0 734
#define FV1 333
#define FV2 443
#define FV3 555
#define FV4 678

__device__ __forceinline__ const float* d_row(int k,
                                              const float* vt,
                                              const float* sd,
                                              const float* pd) {
    // D[k] row of the combined [146][2334] basis
    return (k == 0) ? vt : (k <= 10 ? sd + (size_t)(k-1)*(NV*3)
                                    : pd + (size_t)(k-11)*(NV*3));
}

// ---------------------------------------------------------------------------
// k_fold: ALL batch-independent folds in one kernel. 256 threads/block.
// blockIdx roles:
//   [0,148)    Gq[k][c][q] = sum_v D[k][3v+q]*Jreg[v][c>>4]*wts[v][c&15]
//              (P computed inline; rows 146..147 stored as zeros)
//   [148,280)  SJ[480]/JT[48]: 4 outputs/block, one per wave
//   [280,344)  WJ[256] = sum_v Jreg[v,J]*w[v,j]: 4 outputs/block
//   344        Dfing[146][15], Wfing[5][16] gathers
// ---------------------------------------------------------------------------
__launch_bounds__(256)
__global__ void k_fold(const float* __restrict__ vt,
                       const float* __restrict__ sd,
                       const float* __restrict__ pd,
                       const float* __restrict__ jreg,
                       const float* __restrict__ wts,
                       float* __restrict__ SJ, float* __restrict__ JT,
                       float* __restrict__ WJ, float* __restrict__ Gq,
                       float* __restrict__ Dfing, float* __restrict__ Wfing)
{
    const int o = blockIdx.x;
    const int tid = threadIdx.x;

    if (o < NKP) {
        const int k = o;
        float a0 = 0.f, a1 = 0.f, a2 = 0.f;
        if (k < NK) {
            const float* Drow = d_row(k, vt, sd, pd);
            const int J = tid >> 4, j = tid & 15;
            #pragma unroll 4
            for (int v = 0; v < NV; ++v) {
                float pv = jreg[v*16 + J] * wts[v*16 + j];
                a0 += Drow[3*v+0] * pv;
                a1 += Drow[3*v+1] * pv;
                a2 += Drow[3*v+2] * pv;
            }
        }
        float* g = Gq + ((size_t)k*256 + tid)*3;
        g[0] = a0; g[1] = a1; g[2] = a2;
    } else if (o < 280) {
        const int idx = (o - 148)*4 + (tid >> 6);   // 0..527
        const int t = tid & 63;
        const float* src; int jc;
        if (idx < 480) { int k = idx / 48; jc = idx % 48; src = sd + (size_t)k*(NV*3); }
        else           { jc = idx - 480;              src = vt; }
        int j = jc / 3, c = jc % 3;
        float acc = 0.f;
        for (int v = t; v < NV; v += 64)
            acc += src[3*v + c] * jreg[v*16 + j];
        for (int off = 32; off; off >>= 1) acc += __shfl_down(acc, off, 64);
        if (t == 0) { if (idx < 480) SJ[idx] = acc; else JT[jc] = acc; }
    } else if (o < 344) {
        const int cidx = (o - 280)*4 + (tid >> 6);  // 0..255
        const int t = tid & 63;
        const int J = cidx >> 4, j = cidx & 15;
        float acc = 0.f;
        for (int v = t; v < NV; v += 64)
            acc += jreg[v*16 + J] * wts[v*16 + j];
        for (int off = 32; off; off >>= 1) acc += __shfl_down(acc, off, 64);
        if (t == 0) WJ[cidx] = acc;
    } else {
        const int fv[5] = {FV0, FV1, FV2, FV3, FV4};
        for (int e = tid; e < NK*15; e += 256) {
            int k = e / 15, r = e % 15, f = r / 3, q = r % 3;
            Dfing[e] = d_row(k, vt, sd, pd)[3*fv[f] + q];
        }
        if (tid < 80) {
            int f = tid >> 4, j = tid & 15;
            Wfing[tid] = wts[fv[f]*16 + j];
        }
    }
}

// ---------------------------------------------------------------------------
// kC: everything per-batch. 256 threads, GC=8 batches/block.
// Phase 1: pose PCA + Rodrigues + joint chain -> coef[148], A[16][12] (LDS)
// Phase 2: S[g][c][q] = sum_k coef[g][k] * Gq[k][c][q]   (c=tid)
// Phase 3: joints = A (.) S + A[.,3] (.) WJ  -> out[0..15]
// Phase 4: 5 finger verts via Dfing/Wfing   -> out[16..20]
// LDS: phase-1 scratch and s_S aliased in one union -> ~39.5 KB total.
// ---------------------------------------------------------------------------
__launch_bounds__(256)
__global__ void kC(const float* __restrict__ beta,
                   const float* __restrict__ theta,
                   const float* __restrict__ hm,
                   const float* __restrict__ hc,
                   const float* __restrict__ SJ,
                   const float* __restrict__ JT,
                   const float* __restrict__ WJ,
                   const float* __restrict__ Gq,
                   const float* __restrict__ Dfing,
                   const float* __restrict__ Wfing,
                   float* __restrict__ out,
                   int Btot)
{
    const int tid = threadIdx.x;
    const int w = tid >> 6, t = tid & 63;
    const int b0 = blockIdx.x * GC;

    // persistent LDS
    __shared__ float s_SJ[480];
    __shared__ float s_JT[48];
    __shared__ float s_WJ[256];
    __shared__ float s_beta[GC][10];
    __shared__ __align__(16) float s_coef[GC][152];  // padded; [146..151]=0
    __shared__ float s_A[GC][192];
    __shared__ float s_vpf[GC][16];
    // union: phase-1 scratch (17316 B) aliases s_S (24576 B)
    __shared__ __align__(16) char s_un[GC*768*4];
    float* s_S    = (float*)s_un;          // [GC][768] : c*3+q layout
    float* u_hc   = (float*)s_un;          // [2025]
    float* u_th   = u_hc + 2025;           // [GC][48]
    float* u_pose = u_th + GC*48;          // [GC][48]
    float* u_J    = u_pose + GC*48;        // [GC][48]
    float* u_R    = u_J + GC*48;           // [GC][144]

    // ---- stage constants + per-batch inputs ----
    for (int i = tid; i < 2025; i += 256) u_hc[i] = hc[i];
    for (int i = tid; i < 480;  i += 256) s_SJ[i] = SJ[i];
    if (tid < 48) s_JT[tid] = JT[tid];
    s_WJ[tid] = WJ[tid];
    for (int i = tid; i < GC*48; i += 256) {
        int g = i / 48, tt = i % 48, b = b0 + g;
        u_th[g*48 + tt] = (b < Btot) ? theta[(size_t)b*48 + tt] : 0.f;
    }
    for (int i = tid; i < GC*10; i += 256) {
        int g = i / 10, k = i % 10, b = b0 + g;
        s_beta[g][k] = (b < Btot) ? beta[(size_t)b*10 + k] : 0.f;
    }
    for (int i = tid; i < GC*152; i += 256) ((float*)s_coef)[i] = 0.f;
    __syncthreads();

    // ---- phase 1: per-batch small work; wave w handles g = pp*4 + w ----
    #pragma unroll
    for (int pp = 0; pp < 2; ++pp) {
        int g = pp*4 + w;
        int b = b0 + g;
        if (b < Btot) {
            float* pose = u_pose + g*48;
            float* Jg   = u_J + g*48;
            float* Rg   = u_R + g*144;
            const float* th = u_th + g*48;
            if (t < 3) pose[t] = th[t];
            if (t < 45) {
                float acc = hm[t];
                #pragma unroll 9
                for (int k = 0; k < 45; ++k) acc += th[3+k] * u_hc[k*45 + t];
                pose[3+t] = acc;
            }
            if (t < 48) {
                float acc = s_JT[t];
                #pragma unroll
                for (int k = 0; k < 10; ++k) acc += s_beta[g][k] * s_SJ[k*48 + t];
                Jg[t] = acc;
            }
            if (t < 10) s_coef[g][1+t] = s_beta[g][t];
            if (t == 10) s_coef[g][0] = 1.f;
            if (t < 16) {
                float rx = pose[3*t], ry = pose[3*t+1], rz = pose[3*t+2];
                float ex = rx + 1e-8f, ey = ry + 1e-8f, ez = rz + 1e-8f;
                float angle = sqrtf(ex*ex + ey*ey + ez*ez);
                float inv = 1.f / angle;
                float x = rx*inv, y = ry*inv, z = rz*inv;
                float s  = sinf(angle);
                float c1 = 1.f - cosf(angle);
                float R[9];
                R[0] = 1.f + c1*(-(z*z + y*y));
                R[1] = -s*z + c1*(x*y);
                R[2] =  s*y + c1*(x*z);
                R[3] =  s*z + c1*(x*y);
                R[4] = 1.f + c1*(-(x*x + z*z));
                R[5] = -s*x + c1*(y*z);
                R[6] = -s*y + c1*(x*z);
                R[7] =  s*x + c1*(y*z);
                R[8] = 1.f + c1*(-(x*x + y*y));
                #pragma unroll
                for (int i = 0; i < 9; ++i) Rg[t*9 + i] = R[i];
                if (t >= 1) {
                    #pragma unroll
                    for (int i = 0; i < 9; ++i)
                        s_coef[g][11 + (t-1)*9 + i] = R[i] - ((i % 4 == 0) ? 1.f : 0.f);
                }
            }
            // NOTE: lanes 0..15 of the same wave proceed; wave-synchronous, no barrier
            if (t < 16) {
                float res[12];
                #pragma unroll
                for (int p = 0; p < 3; ++p) {
                    res[p*4+0] = Rg[p*3+0];
                    res[p*4+1] = Rg[p*3+1];
                    res[p*4+2] = Rg[p*3+2];
                    res[p*4+3] = Jg[p];
                }
                if (t >= 1) {
                    int start = ((t-1)/3)*3 + 1;
                    int d = t - start;          // 0..2
                    for (int s = 0; s < 3; ++s) {
                        if (s <= d) {
                            int a  = start + s;
                            int pa = (s == 0) ? 0 : (a - 1);
                            float ax = Jg[a*3+0] - Jg[pa*3+0];
                            float ay = Jg[a*3+1] - Jg[pa*3+1];
                            float az = Jg[a*3+2] - Jg[pa*3+2];
                            float nr[12];
                            #pragma unroll
                            for (int p = 0; p < 3; ++p) {
                                float r0 = res[p*4+0], r1 = res[p*4+1], r2 = res[p*4+2];
                                #pragma unroll
                                for (int q = 0; q < 3; ++q)
                                    nr[p*4+q] = r0*Rg[a*9+q] + r1*Rg[a*9+3+q] + r2*Rg[a*9+6+q];
                                nr[p*4+3] = r0*ax + r1*ay + r2*az + res[p*4+3];
                            }
                            #pragma unroll
                            for (int q = 0; q < 12; ++q) res[q] = nr[q];
                        }
                    }
                }
                float jx = Jg[t*3+0], jy = Jg[t*3+1], jz = Jg[t*3+2];
                #pragma unroll
                for (int p = 0; p < 3; ++p) {
                    float r0 = res[p*4+0], r1 = res[p*4+1], r2 = res[p*4+2];
                    float ib = r0*jx + r1*jy + r2*jz;
                    s_A[g][t*12 + p*4+0] = r0;
                    s_A[g][t*12 + p*4+1] = r1;
                    s_A[g][t*12 + p*4+2] = r2;
                    s_A[g][t*12 + p*4+3] = res[p*4+3] - ib;
                }
            }
        }
    }
    __syncthreads();

    // ---- phase 2: S[g][c][q] = sum_k coef[g][k]*Gq[k][c][q], c = tid ----
    {
        float acc[GC][3];
        #pragma unroll
        for (int g = 0; g < GC; ++g) { acc[g][0]=0.f; acc[g][1]=0.f; acc[g][2]=0.f; }
        for (int k = 0; k < NKP; k += 4) {
            float cfs[GC][4];
            #pragma unroll
            for (int g = 0; g < GC; ++g) {
                float4 cf = *(const float4*)&s_coef[g][k];
                cfs[g][0]=cf.x; cfs[g][1]=cf.y; cfs[g][2]=cf.z; cfs[g][3]=cf.w;
            }
            #pragma unroll
            for (int kk = 0; kk < 4; ++kk) {
                const float* gq = Gq + ((size_t)(k+kk)*256 + tid)*3;
                float g0 = gq[0], g1 = gq[1], g2 = gq[2];
                #pragma unroll
                for (int g = 0; g < GC; ++g) {
                    float cf = cfs[g][kk];
                    acc[g][0] += cf*g0; acc[g][1] += cf*g1; acc[g][2] += cf*g2;
                }
            }
        }
        __syncthreads();   // phase-1 LDS (union) no longer needed; safe to overwrite
        #pragma unroll
        for (int g = 0; g < GC; ++g) {
            s_S[g*768 + tid*3 + 0] = acc[g][0];
            s_S[g*768 + tid*3 + 1] = acc[g][1];
            s_S[g*768 + tid*3 + 2] = acc[g][2];
        }
    }
    __syncthreads();

    // ---- phase 3: joints[b,J,p] ----
    for (int o = tid; o < GC*48; o += 256) {
        int g = o / 48, rem = o % 48, J = rem / 3, p = rem % 3;
        int b = b0 + g;
        if (b < Btot) {
            const float* Ag = s_A[g];
            const float* Sg = s_S + g*768 + J*48;  // 16 j x 3 q contiguous
            float val = 0.f;
            #pragma unroll
            for (int j = 0; j < 16; ++j) {
                val += Ag[j*12 + p*4 + 0] * Sg[j*3+0]
                     + Ag[j*12 + p*4 + 1] * Sg[j*3+1]
                     + Ag[j*12 + p*4 + 2] * Sg[j*3+2]
                     + Ag[j*12 + p*4 + 3] * s_WJ[J*16 + j];
            }
            out[(size_t)b*63 + J*3 + p] = val;
        }
    }

    // ---- phase 4: finger vertices ----
    if (tid < GC*15) {
        int g = tid / 15, r = tid % 15;
        float acc = 0.f;
        #pragma unroll 4
        for (int k = 0; k < NK; ++k) acc += s_coef[g][k] * Dfing[k*15 + r];
        s_vpf[g][r] = acc;
    }
    __syncthreads();
    if (tid < GC*15) {
        int g = tid / 15, r = tid % 15, f = r / 3, p = r % 3;
        int b = b0 + g;
        if (b < Btot) {
            const float* Ag = s_A[g];
            float vx = s_vpf[g][f*3+0], vy = s_vpf[g][f*3+1], vz = s_vpf[g][f*3+2];
            float val = 0.f;
            #pragma unroll
            for (int j = 0; j < 16; ++j) {
                float wj = Wfing[f*16 + j];
                val += wj * (Ag[j*12 + p*4 + 0]*vx +
                             Ag[j*12 + p*4 + 1]*vy +
                             Ag[j*12 + p*4 + 2]*vz +
                             Ag[j*12 + p*4 + 3]);
            }
            out[(size_t)b*63 + (16+f)*3 + p] = val;
        }
    }
}

extern "C" void kernel_launch(void* const* d_in, const int* in_sizes, int n_in,
                              void* d_out, int out_size, void* d_ws, size_t ws_size,
                              hipStream_t stream) {
    const float* beta       = (const float*)d_in[0];
    const float* theta      = (const float*)d_in[1];
    const float* v_template = (const float*)d_in[2];
    const float* shapedirs  = (const float*)d_in[3];
    const float* posedirs   = (const float*)d_in[4];
    const float* J_reg      = (const float*)d_in[5];
    const float* weights    = (const float*)d_in[6];
    const float* hands_mean = (const float*)d_in[7];
    const float* hands_comp = (const float*)d_in[8];
    float* out = (float*)d_out;

    const int B = in_sizes[0] / 10;

    // workspace layout (floats)
    float* W = (float*)d_ws;
    float* SJ    = W;                    // 480
    float* JT    = W + 480;              // 48
    float* WJ    = W + 528;              // 256
    float* Dfing = W + 784;              // 146*15 = 2190
    float* Wfing = W + 2974;             // 80
    float* Gq    = W + 3072;             // 148*256*3 = 113664 (16B-aligned)

    k_fold<<<345, 256, 0, stream>>>(v_template, shapedirs, posedirs, J_reg, weights,
                                    SJ, JT, WJ, Gq, Dfing, Wfing);
    kC<<<(B + GC - 1)/GC, 256, 0, stream>>>(beta, theta, hands_mean, hands_comp,
                                            SJ, JT, WJ, Gq, Dfing, Wfing, out, B);
}

// Round 8
// 140.456 us; speedup vs baseline: 1.2986x; 1.2986x over previous
//
#include <hip/hip_runtime.h>

#define NV  778
#define NBP 135
#define NK  146    // coef: 1 (template) + 10 (beta) + 135 (pose_feature)
#define NKQ 152    // Gq rows padded to multiple of 8 (rows 146..151 zero)
#define GC  8      // batches per kC block
#define VCH 98     // v-chunk per Gq fold block (8 chunks cover 778)

// Finger vertex ids
#define FV0 734
#define FV1 333
#define FV2 443
#define FV3 555
#define FV4 678

__device__ __forceinline__ const float* d_row(int k,
                                              const float* vt,
                                              const float* sd,
                                              const float* pd) {
    // D[k] row of the combined [146][2334] basis
    return (k == 0) ? vt : (k <= 10 ? sd + (size_t)(k-1)*(NV*3)
                                    : pd + (size_t)(k-11)*(NV*3));
}

// ---------------------------------------------------------------------------
// k_fold: ALL batch-independent folds. 256 threads/block. blockIdx roles:
//   [0,1168)     Gq[k][c][q] += sum_{v in chunk} D[k][3v+q]*Jreg[v][c>>4]*wts[v][c&15]
//                k = o>>3, chunk = o&7  (Gq pre-zeroed by hipMemsetAsync;
//                atomicAdd merge, 8 adds/address)
//   [1168,1300)  SJ[480]/JT[48]: 4 dots/block, one per wave
//   [1300,1364)  WJ[256] = sum_v Jreg[v,J]*w[v,j]: 4 dots/block
//   1364         Dfing[146][15], Wfing[5][16] gathers
// ---------------------------------------------------------------------------
__launch_bounds__(256)
__global__ void k_fold(const float* __restrict__ vt,
                       const float* __restrict__ sd,
                       const float* __restrict__ pd,
                       const float* __restrict__ jreg,
                       const float* __restrict__ wts,
                       float* __restrict__ SJ, float* __restrict__ JT,
                       float* __restrict__ WJ, float* __restrict__ Gq,
                       float* __restrict__ Dfing, float* __restrict__ Wfing)
{
    const int o = blockIdx.x;
    const int tid = threadIdx.x;

    if (o < 1168) {
        const int k = o >> 3, chunk = o & 7;
        const int J = tid >> 4, j = tid & 15;
        const float* Drow = d_row(k, vt, sd, pd);
        const int v0 = chunk * VCH;
        const int v1 = (v0 + VCH < NV) ? (v0 + VCH) : NV;
        float a0 = 0.f, a1 = 0.f, a2 = 0.f;
        #pragma unroll 4
        for (int v = v0; v < v1; ++v) {
            float pv = jreg[v*16 + J] * wts[v*16 + j];
            a0 += Drow[3*v+0] * pv;
            a1 += Drow[3*v+1] * pv;
            a2 += Drow[3*v+2] * pv;
        }
        float* gp = Gq + ((size_t)k*256 + tid)*3;
        atomicAdd(gp+0, a0);
        atomicAdd(gp+1, a1);
        atomicAdd(gp+2, a2);
    } else if (o < 1300) {
        const int idx = (o - 1168)*4 + (tid >> 6);   // 0..527
        const int t = tid & 63;
        const float* src; int jc;
        if (idx < 480) { int k = idx / 48; jc = idx % 48; src = sd + (size_t)k*(NV*3); }
        else           { jc = idx - 480;              src = vt; }
        int j = jc / 3, c = jc % 3;
        float acc = 0.f;
        for (int v = t; v < NV; v += 64)
            acc += src[3*v + c] * jreg[v*16 + j];
        for (int off = 32; off; off >>= 1) acc += __shfl_down(acc, off, 64);
        if (t == 0) { if (idx < 480) SJ[idx] = acc; else JT[jc] = acc; }
    } else if (o < 1364) {
        const int cidx = (o - 1300)*4 + (tid >> 6);  // 0..255
        const int t = tid & 63;
        const int J = cidx >> 4, j = cidx & 15;
        float acc = 0.f;
        for (int v = t; v < NV; v += 64)
            acc += jreg[v*16 + J] * wts[v*16 + j];
        for (int off = 32; off; off >>= 1) acc += __shfl_down(acc, off, 64);
        if (t == 0) WJ[cidx] = acc;
    } else {
        const int fv[5] = {FV0, FV1, FV2, FV3, FV4};
        for (int e = tid; e < NK*15; e += 256) {
            int k = e / 15, r = e % 15, f = r / 3, q = r % 3;
            Dfing[e] = d_row(k, vt, sd, pd)[3*fv[f] + q];
        }
        if (tid < 80) {
            int f = tid >> 4, j = tid & 15;
            Wfing[tid] = wts[fv[f]*16 + j];
        }
    }
}

// ---------------------------------------------------------------------------
// kC: everything per-batch. 256 threads, GC=8 batches/block.
// Phase 1: pose PCA + Rodrigues + joint chain -> coef[152], A[16][12] (LDS)
// Phase 2: S[g][c][q] = sum_k coef[g][k]*Gq[k][c][q]  (k unrolled x8,
//          8 dwordx3 loads hoisted per group for MLP)
// Phase 3: joints = A (.) S + A[.,3] (.) WJ  -> out[0..15]
// Phase 4: 5 finger verts via Dfing/Wfing   -> out[16..20]
// ---------------------------------------------------------------------------
__launch_bounds__(256)
__global__ void kC(const float* __restrict__ beta,
                   const float* __restrict__ theta,
                   const float* __restrict__ hm,
                   const float* __restrict__ hc,
                   const float* __restrict__ SJ,
                   const float* __restrict__ JT,
                   const float* __restrict__ WJ,
                   const float* __restrict__ Gq,
                   const float* __restrict__ Dfing,
                   const float* __restrict__ Wfing,
                   float* __restrict__ out,
                   int Btot)
{
    const int tid = threadIdx.x;
    const int w = tid >> 6, t = tid & 63;
    const int b0 = blockIdx.x * GC;

    // persistent LDS
    __shared__ float s_SJ[480];
    __shared__ float s_JT[48];
    __shared__ float s_WJ[256];
    __shared__ float s_beta[GC][10];
    __shared__ __align__(16) float s_coef[GC][152];  // padded; [146..151]=0
    __shared__ float s_A[GC][192];
    __shared__ float s_vpf[GC][16];
    // union: phase-1 scratch (17316 B) aliases s_S (24576 B)
    __shared__ __align__(16) char s_un[GC*768*4];
    float* s_S    = (float*)s_un;          // [GC][768] : c*3+q layout
    float* u_hc   = (float*)s_un;          // [2025]
    float* u_th   = u_hc + 2025;           // [GC][48]
    float* u_pose = u_th + GC*48;          // [GC][48]
    float* u_J    = u_pose + GC*48;        // [GC][48]
    float* u_R    = u_J + GC*48;           // [GC][144]

    // ---- stage constants + per-batch inputs ----
    for (int i = tid; i < 2025; i += 256) u_hc[i] = hc[i];
    for (int i = tid; i < 480;  i += 256) s_SJ[i] = SJ[i];
    if (tid < 48) s_JT[tid] = JT[tid];
    s_WJ[tid] = WJ[tid];
    for (int i = tid; i < GC*48; i += 256) {
        int g = i / 48, tt = i % 48, b = b0 + g;
        u_th[g*48 + tt] = (b < Btot) ? theta[(size_t)b*48 + tt] : 0.f;
    }
    for (int i = tid; i < GC*10; i += 256) {
        int g = i / 10, k = i % 10, b = b0 + g;
        s_beta[g][k] = (b < Btot) ? beta[(size_t)b*10 + k] : 0.f;
    }
    for (int i = tid; i < GC*152; i += 256) ((float*)s_coef)[i] = 0.f;
    __syncthreads();

    // ---- phase 1: per-batch small work; wave w handles g = pp*4 + w ----
    #pragma unroll
    for (int pp = 0; pp < 2; ++pp) {
        int g = pp*4 + w;
        int b = b0 + g;
        if (b < Btot) {
            float* pose = u_pose + g*48;
            float* Jg   = u_J + g*48;
            float* Rg   = u_R + g*144;
            const float* th = u_th + g*48;
            if (t < 3) pose[t] = th[t];
            if (t < 45) {
                float acc = hm[t];
                #pragma unroll 9
                for (int k = 0; k < 45; ++k) acc += th[3+k] * u_hc[k*45 + t];
                pose[3+t] = acc;
            }
            if (t < 48) {
                float acc = s_JT[t];
                #pragma unroll
                for (int k = 0; k < 10; ++k) acc += s_beta[g][k] * s_SJ[k*48 + t];
                Jg[t] = acc;
            }
            if (t < 10) s_coef[g][1+t] = s_beta[g][t];
            if (t == 10) s_coef[g][0] = 1.f;
            if (t < 16) {
                float rx = pose[3*t], ry = pose[3*t+1], rz = pose[3*t+2];
                float ex = rx + 1e-8f, ey = ry + 1e-8f, ez = rz + 1e-8f;
                float angle = sqrtf(ex*ex + ey*ey + ez*ez);
                float inv = 1.f / angle;
                float x = rx*inv, y = ry*inv, z = rz*inv;
                float s  = sinf(angle);
                float c1 = 1.f - cosf(angle);
                float R[9];
                R[0] = 1.f + c1*(-(z*z + y*y));
                R[1] = -s*z + c1*(x*y);
                R[2] =  s*y + c1*(x*z);
                R[3] =  s*z + c1*(x*y);
                R[4] = 1.f + c1*(-(x*x + z*z));
                R[5] = -s*x + c1*(y*z);
                R[6] = -s*y + c1*(x*z);
                R[7] =  s*x + c1*(y*z);
                R[8] = 1.f + c1*(-(x*x + y*y));
                #pragma unroll
                for (int i = 0; i < 9; ++i) Rg[t*9 + i] = R[i];
                if (t >= 1) {
                    #pragma unroll
                    for (int i = 0; i < 9; ++i)
                        s_coef[g][11 + (t-1)*9 + i] = R[i] - ((i % 4 == 0) ? 1.f : 0.f);
                }
            }
            if (t < 16) {
                float res[12];
                #pragma unroll
                for (int p = 0; p < 3; ++p) {
                    res[p*4+0] = Rg[p*3+0];
                    res[p*4+1] = Rg[p*3+1];
                    res[p*4+2] = Rg[p*3+2];
                    res[p*4+3] = Jg[p];
                }
                if (t >= 1) {
                    int start = ((t-1)/3)*3 + 1;
                    int d = t - start;          // 0..2
                    for (int s = 0; s < 3; ++s) {
                        if (s <= d) {
                            int a  = start + s;
                            int pa = (s == 0) ? 0 : (a - 1);
                            float ax = Jg[a*3+0] - Jg[pa*3+0];
                            float ay = Jg[a*3+1] - Jg[pa*3+1];
                            float az = Jg[a*3+2] - Jg[pa*3+2];
                            float nr[12];
                            #pragma unroll
                            for (int p = 0; p < 3; ++p) {
                                float r0 = res[p*4+0], r1 = res[p*4+1], r2 = res[p*4+2];
                                #pragma unroll
                                for (int q = 0; q < 3; ++q)
                                    nr[p*4+q] = r0*Rg[a*9+q] + r1*Rg[a*9+3+q] + r2*Rg[a*9+6+q];
                                nr[p*4+3] = r0*ax + r1*ay + r2*az + res[p*4+3];
                            }
                            #pragma unroll
                            for (int q = 0; q < 12; ++q) res[q] = nr[q];
                        }
                    }
                }
                float jx = Jg[t*3+0], jy = Jg[t*3+1], jz = Jg[t*3+2];
                #pragma unroll
                for (int p = 0; p < 3; ++p) {
                    float r0 = res[p*4+0], r1 = res[p*4+1], r2 = res[p*4+2];
                    float ib = r0*jx + r1*jy + r2*jz;
                    s_A[g][t*12 + p*4+0] = r0;
                    s_A[g][t*12 + p*4+1] = r1;
                    s_A[g][t*12 + p*4+2] = r2;
                    s_A[g][t*12 + p*4+3] = res[p*4+3] - ib;
                }
            }
        }
    }
    __syncthreads();

    // ---- phase 2: S[g][c][q] = sum_k coef[g][k]*Gq[k][c][q], c = tid ----
    {
        float acc[GC][3];
        #pragma unroll
        for (int g = 0; g < GC; ++g) { acc[g][0]=0.f; acc[g][1]=0.f; acc[g][2]=0.f; }
        for (int k = 0; k < NKQ; k += 8) {
            float g0[8], g1[8], g2[8];
            #pragma unroll
            for (int kk = 0; kk < 8; ++kk) {
                const float* gq = Gq + ((size_t)(k+kk)*256 + tid)*3;
                g0[kk] = gq[0]; g1[kk] = gq[1]; g2[kk] = gq[2];
            }
            #pragma unroll
            for (int g = 0; g < GC; ++g) {
                float4 cA = *(const float4*)&s_coef[g][k];
                float4 cB = *(const float4*)&s_coef[g][k+4];
                float cf[8] = {cA.x,cA.y,cA.z,cA.w, cB.x,cB.y,cB.z,cB.w};
                #pragma unroll
                for (int kk = 0; kk < 8; ++kk) {
                    acc[g][0] += cf[kk]*g0[kk];
                    acc[g][1] += cf[kk]*g1[kk];
                    acc[g][2] += cf[kk]*g2[kk];
                }
            }
        }
        __syncthreads();   // phase-1 LDS (union) dead; safe to overwrite
        #pragma unroll
        for (int g = 0; g < GC; ++g) {
            s_S[g*768 + tid*3 + 0] = acc[g][0];
            s_S[g*768 + tid*3 + 1] = acc[g][1];
            s_S[g*768 + tid*3 + 2] = acc[g][2];
        }
    }
    __syncthreads();

    // ---- phase 3: joints[b,J,p] ----
    for (int o = tid; o < GC*48; o += 256) {
        int g = o / 48, rem = o % 48, J = rem / 3, p = rem % 3;
        int b = b0 + g;
        if (b < Btot) {
            const float* Ag = s_A[g];
            const float* Sg = s_S + g*768 + J*48;  // 16 j x 3 q contiguous
            float val = 0.f;
            #pragma unroll
            for (int j = 0; j < 16; ++j) {
                val += Ag[j*12 + p*4 + 0] * Sg[j*3+0]
                     + Ag[j*12 + p*4 + 1] * Sg[j*3+1]
                     + Ag[j*12 + p*4 + 2] * Sg[j*3+2]
                     + Ag[j*12 + p*4 + 3] * s_WJ[J*16 + j];
            }
            out[(size_t)b*63 + J*3 + p] = val;
        }
    }

    // ---- phase 4: finger vertices ----
    if (tid < GC*15) {
        int g = tid / 15, r = tid % 15;
        float acc = 0.f;
        #pragma unroll 4
        for (int k = 0; k < NK; ++k) acc += s_coef[g][k] * Dfing[k*15 + r];
        s_vpf[g][r] = acc;
    }
    __syncthreads();
    if (tid < GC*15) {
        int g = tid / 15, r = tid % 15, f = r / 3, p = r % 3;
        int b = b0 + g;
        if (b < Btot) {
            const float* Ag = s_A[g];
            float vx = s_vpf[g][f*3+0], vy = s_vpf[g][f*3+1], vz = s_vpf[g][f*3+2];
            float val = 0.f;
            #pragma unroll
            for (int j = 0; j < 16; ++j) {
                float wj = Wfing[f*16 + j];
                val += wj * (Ag[j*12 + p*4 + 0]*vx +
                             Ag[j*12 + p*4 + 1]*vy +
                             Ag[j*12 + p*4 + 2]*vz +
                             Ag[j*12 + p*4 + 3]);
            }
            out[(size_t)b*63 + (16+f)*3 + p] = val;
        }
    }
}

extern "C" void kernel_launch(void* const* d_in, const int* in_sizes, int n_in,
                              void* d_out, int out_size, void* d_ws, size_t ws_size,
                              hipStream_t stream) {
    const float* beta       = (const float*)d_in[0];
    const float* theta      = (const float*)d_in[1];
    const float* v_template = (const float*)d_in[2];
    const float* shapedirs  = (const float*)d_in[3];
    const float* posedirs   = (const float*)d_in[4];
    const float* J_reg      = (const float*)d_in[5];
    const float* weights    = (const float*)d_in[6];
    const float* hands_mean = (const float*)d_in[7];
    const float* hands_comp = (const float*)d_in[8];
    float* out = (float*)d_out;

    const int B = in_sizes[0] / 10;

    // workspace layout (floats)
    float* W = (float*)d_ws;
    float* SJ    = W;                    // 480
    float* JT    = W + 480;              // 48
    float* WJ    = W + 528;              // 256
    float* Dfing = W + 784;              // 146*15 = 2190
    float* Wfing = W + 2974;             // 80
    float* Gq    = W + 3072;             // 152*256*3 = 116736 (16B-aligned)

    hipMemsetAsync(Gq, 0, (size_t)NKQ*768*sizeof(float), stream);
    k_fold<<<1365, 256, 0, stream>>>(v_template, shapedirs, posedirs, J_reg, weights,
                                     SJ, JT, WJ, Gq, Dfing, Wfing);
    kC<<<(B + GC - 1)/GC, 256, 0, stream>>>(beta, theta, hands_mean, hands_comp,
                                            SJ, JT, WJ, Gq, Dfing, Wfing, out, B);
}

// Round 9
// 137.805 us; speedup vs baseline: 1.3236x; 1.0192x over previous
//
#include <hip/hip_runtime.h>

#define NV  778
#define NBP 135
#define NK  146    // coef: 1 (template) + 10 (beta) + 135 (pose_feature)
#define NKQ 152    // Gq rows padded to multiple of 8 (rows 146..151 zero)
#define GC  4      // batches per kC block
#define VCH 49     // v-chunk per Gq fold block (16 chunks cover 778)

// Finger vertex ids
#define FV0 734
#define FV1 333
#define FV2 443
#define FV3 555
#define FV4 678

__device__ __forceinline__ const float* d_row(int k,
                                              const float* vt,
                                              const float* sd,
                                              const float* pd) {
    // D[k] row of the combined [146][2334] basis
    return (k == 0) ? vt : (k <= 10 ? sd + (size_t)(k-1)*(NV*3)
                                    : pd + (size_t)(k-11)*(NV*3));
}

// ---------------------------------------------------------------------------
// k_fold: ALL batch-independent folds. 256 threads/block. blockIdx roles:
//   [0,2336)     Gq[k][c][q] += sum_{v in chunk} D[k][3v+q]*Jreg[v][c>>4]*wts[v][c&15]
//                k = o>>4, chunk = o&15  (Gq pre-zeroed by hipMemsetAsync;
//                atomicAdd merge, 16 adds/address)
//   [2336,2468)  SJ[480]/JT[48]: 4 dots/block, one per wave
//   [2468,2532)  WJ[256] = sum_v Jreg[v,J]*w[v,j]: 4 dots/block
//   2532         Dfing[146][15], Wfing[5][16] gathers
// ---------------------------------------------------------------------------
__launch_bounds__(256)
__global__ void k_fold(const float* __restrict__ vt,
                       const float* __restrict__ sd,
                       const float* __restrict__ pd,
                       const float* __restrict__ jreg,
                       const float* __restrict__ wts,
                       float* __restrict__ SJ, float* __restrict__ JT,
                       float* __restrict__ WJ, float* __restrict__ Gq,
                       float* __restrict__ Dfing, float* __restrict__ Wfing)
{
    const int o = blockIdx.x;
    const int tid = threadIdx.x;

    if (o < 2336) {
        const int k = o >> 4, chunk = o & 15;
        const int J = tid >> 4, j = tid & 15;
        const float* Drow = d_row(k, vt, sd, pd);
        const int v0 = chunk * VCH;
        const int v1 = (v0 + VCH < NV) ? (v0 + VCH) : NV;
        float a0 = 0.f, a1 = 0.f, a2 = 0.f;
        #pragma unroll 7
        for (int v = v0; v < v1; ++v) {
            float pv = jreg[v*16 + J] * wts[v*16 + j];
            a0 += Drow[3*v+0] * pv;
            a1 += Drow[3*v+1] * pv;
            a2 += Drow[3*v+2] * pv;
        }
        float* gp = Gq + ((size_t)k*256 + tid)*3;
        atomicAdd(gp+0, a0);
        atomicAdd(gp+1, a1);
        atomicAdd(gp+2, a2);
    } else if (o < 2468) {
        const int idx = (o - 2336)*4 + (tid >> 6);   // 0..527
        const int t = tid & 63;
        const float* src; int jc;
        if (idx < 480) { int k = idx / 48; jc = idx % 48; src = sd + (size_t)k*(NV*3); }
        else           { jc = idx - 480;              src = vt; }
        int j = jc / 3, c = jc % 3;
        float acc = 0.f;
        for (int v = t; v < NV; v += 64)
            acc += src[3*v + c] * jreg[v*16 + j];
        for (int off = 32; off; off >>= 1) acc += __shfl_down(acc, off, 64);
        if (t == 0) { if (idx < 480) SJ[idx] = acc; else JT[jc] = acc; }
    } else if (o < 2532) {
        const int cidx = (o - 2468)*4 + (tid >> 6);  // 0..255
        const int t = tid & 63;
        const int J = cidx >> 4, j = cidx & 15;
        float acc = 0.f;
        for (int v = t; v < NV; v += 64)
            acc += jreg[v*16 + J] * wts[v*16 + j];
        for (int off = 32; off; off >>= 1) acc += __shfl_down(acc, off, 64);
        if (t == 0) WJ[cidx] = acc;
    } else {
        const int fv[5] = {FV0, FV1, FV2, FV3, FV4};
        for (int e = tid; e < NK*15; e += 256) {
            int k = e / 15, r = e % 15, f = r / 3, q = r % 3;
            Dfing[e] = d_row(k, vt, sd, pd)[3*fv[f] + q];
        }
        if (tid < 80) {
            int f = tid >> 4, j = tid & 15;
            Wfing[tid] = wts[fv[f]*16 + j];
        }
    }
}

// ---------------------------------------------------------------------------
// kC: everything per-batch. 256 threads, GC=4 batches/block (1024 blocks ->
// 4 blocks/CU). Phase 2 software-pipelined: group-0 Gq loads issued at
// kernel entry (hidden behind staging+phase 1), groups double-buffered.
// ---------------------------------------------------------------------------
__launch_bounds__(256)
__global__ void kC(const float* __restrict__ beta,
                   const float* __restrict__ theta,
                   const float* __restrict__ hm,
                   const float* __restrict__ hc,
                   const float* __restrict__ SJ,
                   const float* __restrict__ JT,
                   const float* __restrict__ WJ,
                   const float* __restrict__ Gq,
                   const float* __restrict__ Dfing,
                   const float* __restrict__ Wfing,
                   float* __restrict__ out,
                   int Btot)
{
    const int tid = threadIdx.x;
    const int w = tid >> 6, t = tid & 63;
    const int b0 = blockIdx.x * GC;

    // persistent LDS
    __shared__ float s_SJ[480];
    __shared__ float s_JT[48];
    __shared__ float s_WJ[256];
    __shared__ float s_beta[GC][10];
    __shared__ __align__(16) float s_coef[GC][152];  // padded; [146..151]=0
    __shared__ float s_A[GC][192];
    __shared__ float s_vpf[GC][16];
    // union: phase-1 scratch (12708 B) aliases s_S (12288 B)
    __shared__ __align__(16) char s_un[3177*4];
    float* s_S    = (float*)s_un;          // [GC][768] : c*3+q layout
    float* u_hc   = (float*)s_un;          // [2025]
    float* u_th   = u_hc + 2025;           // [GC][48]
    float* u_pose = u_th + GC*48;          // [GC][48]
    float* u_J    = u_pose + GC*48;        // [GC][48]
    float* u_R    = u_J + GC*48;           // [GC][144]

    // ---- prefetch Gq group 0 (independent of all LDS work) ----
    float cur0[8], cur1[8], cur2[8];
    #pragma unroll
    for (int kk = 0; kk < 8; ++kk) {
        const float* gq = Gq + ((size_t)kk*256 + tid)*3;
        cur0[kk] = gq[0]; cur1[kk] = gq[1]; cur2[kk] = gq[2];
    }

    // ---- stage constants + per-batch inputs ----
    for (int i = tid; i < 2025; i += 256) u_hc[i] = hc[i];
    for (int i = tid; i < 480;  i += 256) s_SJ[i] = SJ[i];
    if (tid < 48) s_JT[tid] = JT[tid];
    s_WJ[tid] = WJ[tid];
    for (int i = tid; i < GC*48; i += 256) {
        int g = i / 48, tt = i % 48, b = b0 + g;
        u_th[g*48 + tt] = (b < Btot) ? theta[(size_t)b*48 + tt] : 0.f;
    }
    for (int i = tid; i < GC*10; i += 256) {
        int g = i / 10, k = i % 10, b = b0 + g;
        s_beta[g][k] = (b < Btot) ? beta[(size_t)b*10 + k] : 0.f;
    }
    for (int i = tid; i < GC*152; i += 256) ((float*)s_coef)[i] = 0.f;
    __syncthreads();

    // ---- phase 1: per-batch small work; wave w handles g = w ----
    {
        const int g = w;
        const int b = b0 + g;
        if (b < Btot) {
            float* pose = u_pose + g*48;
            float* Jg   = u_J + g*48;
            float* Rg   = u_R + g*144;
            const float* th = u_th + g*48;
            if (t < 3) pose[t] = th[t];
            if (t < 45) {
                float acc = hm[t];
                #pragma unroll 9
                for (int k = 0; k < 45; ++k) acc += th[3+k] * u_hc[k*45 + t];
                pose[3+t] = acc;
            }
            if (t < 48) {
                float acc = s_JT[t];
                #pragma unroll
                for (int k = 0; k < 10; ++k) acc += s_beta[g][k] * s_SJ[k*48 + t];
                Jg[t] = acc;
            }
            if (t < 10) s_coef[g][1+t] = s_beta[g][t];
            if (t == 10) s_coef[g][0] = 1.f;
            if (t < 16) {
                float rx = pose[3*t], ry = pose[3*t+1], rz = pose[3*t+2];
                float ex = rx + 1e-8f, ey = ry + 1e-8f, ez = rz + 1e-8f;
                float angle = sqrtf(ex*ex + ey*ey + ez*ez);
                float inv = 1.f / angle;
                float x = rx*inv, y = ry*inv, z = rz*inv;
                float s  = sinf(angle);
                float c1 = 1.f - cosf(angle);
                float R[9];
                R[0] = 1.f + c1*(-(z*z + y*y));
                R[1] = -s*z + c1*(x*y);
                R[2] =  s*y + c1*(x*z);
                R[3] =  s*z + c1*(x*y);
                R[4] = 1.f + c1*(-(x*x + z*z));
                R[5] = -s*x + c1*(y*z);
                R[6] = -s*y + c1*(x*z);
                R[7] =  s*x + c1*(y*z);
                R[8] = 1.f + c1*(-(x*x + y*y));
                #pragma unroll
                for (int i = 0; i < 9; ++i) Rg[t*9 + i] = R[i];
                if (t >= 1) {
                    #pragma unroll
                    for (int i = 0; i < 9; ++i)
                        s_coef[g][11 + (t-1)*9 + i] = R[i] - ((i % 4 == 0) ? 1.f : 0.f);
                }
            }
            // wave-synchronous: Rg/Jg visible to lanes of same wave
            if (t < 16) {
                float res[12];
                #pragma unroll
                for (int p = 0; p < 3; ++p) {
                    res[p*4+0] = Rg[p*3+0];
                    res[p*4+1] = Rg[p*3+1];
                    res[p*4+2] = Rg[p*3+2];
                    res[p*4+3] = Jg[p];
                }
                if (t >= 1) {
                    int start = ((t-1)/3)*3 + 1;
                    int d = t - start;          // 0..2
                    for (int s = 0; s < 3; ++s) {
                        if (s <= d) {
                            int a  = start + s;
                            int pa = (s == 0) ? 0 : (a - 1);
                            float ax = Jg[a*3+0] - Jg[pa*3+0];
                            float ay = Jg[a*3+1] - Jg[pa*3+1];
                            float az = Jg[a*3+2] - Jg[pa*3+2];
                            float nr[12];
                            #pragma unroll
                            for (int p = 0; p < 3; ++p) {
                                float r0 = res[p*4+0], r1 = res[p*4+1], r2 = res[p*4+2];
                                #pragma unroll
                                for (int q = 0; q < 3; ++q)
                                    nr[p*4+q] = r0*Rg[a*9+q] + r1*Rg[a*9+3+q] + r2*Rg[a*9+6+q];
                                nr[p*4+3] = r0*ax + r1*ay + r2*az + res[p*4+3];
                            }
                            #pragma unroll
                            for (int q = 0; q < 12; ++q) res[q] = nr[q];
                        }
                    }
                }
                float jx = Jg[t*3+0], jy = Jg[t*3+1], jz = Jg[t*3+2];
                #pragma unroll
                for (int p = 0; p < 3; ++p) {
                    float r0 = res[p*4+0], r1 = res[p*4+1], r2 = res[p*4+2];
                    float ib = r0*jx + r1*jy + r2*jz;
                    s_A[g][t*12 + p*4+0] = r0;
                    s_A[g][t*12 + p*4+1] = r1;
                    s_A[g][t*12 + p*4+2] = r2;
                    s_A[g][t*12 + p*4+3] = res[p*4+3] - ib;
                }
            }
        }
    }
    __syncthreads();

    // ---- phase 2: S[g][c][q] = sum_k coef[g][k]*Gq[k][c][q], c = tid ----
    // double-buffered 8-row groups; group 0 already in cur*.
    {
        float acc[GC][3];
        #pragma unroll
        for (int g = 0; g < GC; ++g) { acc[g][0]=0.f; acc[g][1]=0.f; acc[g][2]=0.f; }
        for (int k = 0; k < NKQ; k += 8) {
            float nxt0[8], nxt1[8], nxt2[8];
            if (k + 8 < NKQ) {
                #pragma unroll
                for (int kk = 0; kk < 8; ++kk) {
                    const float* gq = Gq + ((size_t)(k+8+kk)*256 + tid)*3;
                    nxt0[kk] = gq[0]; nxt1[kk] = gq[1]; nxt2[kk] = gq[2];
                }
            }
            #pragma unroll
            for (int g = 0; g < GC; ++g) {
                float4 cA = *(const float4*)&s_coef[g][k];
                float4 cB = *(const float4*)&s_coef[g][k+4];
                float cf[8] = {cA.x,cA.y,cA.z,cA.w, cB.x,cB.y,cB.z,cB.w};
                #pragma unroll
                for (int kk = 0; kk < 8; ++kk) {
                    acc[g][0] += cf[kk]*cur0[kk];
                    acc[g][1] += cf[kk]*cur1[kk];
                    acc[g][2] += cf[kk]*cur2[kk];
                }
            }
            if (k + 8 < NKQ) {
                #pragma unroll
                for (int kk = 0; kk < 8; ++kk) {
                    cur0[kk] = nxt0[kk]; cur1[kk] = nxt1[kk]; cur2[kk] = nxt2[kk];
                }
            }
        }
        __syncthreads();   // phase-1 LDS (union) dead; safe to overwrite
        #pragma unroll
        for (int g = 0; g < GC; ++g) {
            s_S[g*768 + tid*3 + 0] = acc[g][0];
            s_S[g*768 + tid*3 + 1] = acc[g][1];
            s_S[g*768 + tid*3 + 2] = acc[g][2];
        }
    }
    __syncthreads();

    // ---- phase 3: joints[b,J,p] ----
    if (tid < GC*48) {
        int g = tid / 48, rem = tid % 48, J = rem / 3, p = rem % 3;
        int b = b0 + g;
        if (b < Btot) {
            const float* Ag = s_A[g];
            const float* Sg = s_S + g*768 + J*48;  // 16 j x 3 q contiguous
            float val = 0.f;
            #pragma unroll
            for (int j = 0; j < 16; ++j) {
                val += Ag[j*12 + p*4 + 0] * Sg[j*3+0]
                     + Ag[j*12 + p*4 + 1] * Sg[j*3+1]
                     + Ag[j*12 + p*4 + 2] * Sg[j*3+2]
                     + Ag[j*12 + p*4 + 3] * s_WJ[J*16 + j];
            }
            out[(size_t)b*63 + J*3 + p] = val;
        }
    }

    // ---- phase 4: finger vertices ----
    if (tid >= 192 && tid < 192 + GC*15) {
        int r2 = tid - 192;
        int g = r2 / 15, r = r2 % 15;
        float acc = 0.f;
        #pragma unroll 4
        for (int k = 0; k < NK; ++k) acc += s_coef[g][k] * Dfing[k*15 + r];
        s_vpf[g][r] = acc;
    }
    __syncthreads();
    if (tid >= 192 && tid < 192 + GC*15) {
        int r2 = tid - 192;
        int g = r2 / 15, r = r2 % 15, f = r / 3, p = r % 3;
        int b = b0 + g;
        if (b < Btot) {
            const float* Ag = s_A[g];
            float vx = s_vpf[g][f*3+0], vy = s_vpf[g][f*3+1], vz = s_vpf[g][f*3+2];
            float val = 0.f;
            #pragma unroll
            for (int j = 0; j < 16; ++j) {
                float wj = Wfing[f*16 + j];
                val += wj * (Ag[j*12 + p*4 + 0]*vx +
                             Ag[j*12 + p*4 + 1]*vy +
                             Ag[j*12 + p*4 + 2]*vz +
                             Ag[j*12 + p*4 + 3]);
            }
            out[(size_t)b*63 + (16+f)*3 + p] = val;
        }
    }
}

extern "C" void kernel_launch(void* const* d_in, const int* in_sizes, int n_in,
                              void* d_out, int out_size, void* d_ws, size_t ws_size,
                              hipStream_t stream) {
    const float* beta       = (const float*)d_in[0];
    const float* theta      = (const float*)d_in[1];
    const float* v_template = (const float*)d_in[2];
    const float* shapedirs  = (const float*)d_in[3];
    const float* posedirs   = (const float*)d_in[4];
    const float* J_reg      = (const float*)d_in[5];
    const float* weights    = (const float*)d_in[6];
    const float* hands_mean = (const float*)d_in[7];
    const float* hands_comp = (const float*)d_in[8];
    float* out = (float*)d_out;

    const int B = in_sizes[0] / 10;

    // workspace layout (floats)
    float* W = (float*)d_ws;
    float* SJ    = W;                    // 480
    float* JT    = W + 480;              // 48
    float* WJ    = W + 528;              // 256
    float* Dfing = W + 784;              // 146*15 = 2190
    float* Wfing = W + 2974;             // 80
    float* Gq    = W + 3072;             // 152*256*3 = 116736 (16B-aligned)

    hipMemsetAsync(Gq, 0, (size_t)NKQ*768*sizeof(float), stream);
    k_fold<<<2533, 256, 0, stream>>>(v_template, shapedirs, posedirs, J_reg, weights,
                                     SJ, JT, WJ, Gq, Dfing, Wfing);
    kC<<<(B + GC - 1)/GC, 256, 0, stream>>>(beta, theta, hands_mean, hands_comp,
                                            SJ, JT, WJ, Gq, Dfing, Wfing, out, B);
}